// Round 8
// baseline (846.484 us; speedup 1.0000x reference)
//
#include <hip/hip_runtime.h>
#include <hip/hip_bf16.h>

// GCN: h1 = relu(gcnconv(x,W1,b1)); h2 = relu(gcnconv(h1,W2,b2));
// pooled = segment_mean(h2, batch); out = pooled@Wlin + blin
//
// R8: int8 gather table + eighth-wave-per-node (8 lanes x uint4 = whole 128B
// row in one load -> 2 lines/edge, 8 chains/wave) + degree-sorted node order
// (counting sort) to kill inter-stream divergence.

#define FEAT 128
#define GRAPHS 256
#define CH 2048
#define BSH 8
#define MAXNB 512

typedef short bf16x8 __attribute__((ext_vector_type(8)));
typedef float f32x4 __attribute__((ext_vector_type(4)));

__device__ inline unsigned bf16rne(float f) {
    unsigned u = __float_as_uint(f);
    return (u + 0x7FFFu + ((u >> 16) & 1u)) >> 16;
}
__device__ inline float bfl(unsigned u) { return __uint_as_float(u << 16); }
__device__ inline float bfh(unsigned u) { return __uint_as_float(u & 0xFFFF0000u); }

#define SWZ(row, kbyte) ((kbyte) ^ (((row) & 7) << 4))

// ---------------- bucket histogram ----------------
__global__ __launch_bounds__(256) void kb_hist(const int* __restrict__ dst, int E, int NB,
                                               int* __restrict__ bhist) {
    __shared__ int h[MAXNB];
    for (int i = threadIdx.x; i < NB; i += 256) h[i] = 0;
    __syncthreads();
    int stride = gridDim.x * 256;
    for (int i = blockIdx.x * 256 + threadIdx.x; i < E; i += stride)
        atomicAdd(&h[dst[i] >> BSH], 1);
    __syncthreads();
    for (int i = threadIdx.x; i < NB; i += 256)
        if (h[i]) atomicAdd(&bhist[i], h[i]);
}

// ---------------- bucket base scan ----------------
__global__ void kb_scan(const int* __restrict__ bhist, int NB,
                        int* __restrict__ bbase, int* __restrict__ bcur) {
    __shared__ int s[512];
    int t = threadIdx.x;
    int v = (t < NB) ? bhist[t] : 0;
    s[t] = v;
    __syncthreads();
    for (int d = 1; d < 512; d <<= 1) {
        int a = (t >= d) ? s[t - d] : 0;
        __syncthreads();
        s[t] += a;
        __syncthreads();
    }
    if (t < NB) { int e = s[t] - v; bbase[t] = e; bcur[t] = e; }
}

// ---------------- group edges by bucket into staging (packed) ----------------
__global__ __launch_bounds__(256) void kb_group(const int* __restrict__ src,
                                                const int* __restrict__ dst, int E, int NB,
                                                int* __restrict__ bcur,
                                                unsigned* __restrict__ stg) {
    __shared__ int lhist[MAXNB], lcur[MAXNB], gdelta[MAXNB], sc[512];
    __shared__ unsigned lpak[CH];
    __shared__ int gp[CH];
    int t = threadIdx.x;
    int base = blockIdx.x * CH;
    int n = E - base; if (n > CH) n = CH;

    for (int i = t; i < NB; i += 256) lhist[i] = 0;
    __syncthreads();

    unsigned pk[8]; int bk[8]; int nl = 0;
#pragma unroll
    for (int j = 0; j < 8; ++j) {
        int k = j * 256 + t;
        if (k < n) {
            int d = dst[base + k];
            int sv = src[base + k];
            int b = d >> BSH;
            pk[nl] = ((unsigned)(d & ((1 << BSH) - 1)) << 17) | (unsigned)sv;
            bk[nl] = b; nl++;
            atomicAdd(&lhist[b], 1);
        }
    }
    __syncthreads();

    for (int i = t; i < 512; i += 256) sc[i] = (i < NB) ? lhist[i] : 0;
    __syncthreads();
    for (int d = 1; d < 512; d <<= 1) {
        int a0 = (t >= d) ? sc[t - d] : 0;
        int a1 = sc[t + 256 - d];
        __syncthreads();
        sc[t] += a0; sc[t + 256] += a1;
        __syncthreads();
    }
    for (int i = t; i < NB; i += 256) {
        int c = lhist[i];
        int lb = sc[i] - c;
        lcur[i] = lb;
        int g = c ? atomicAdd(&bcur[i], c) : 0;
        gdelta[i] = g - lb;
    }
    __syncthreads();

    for (int j = 0; j < nl; ++j) {
        int b = bk[j];
        int slot = atomicAdd(&lcur[b], 1);
        lpak[slot] = pk[j];
        gp[slot] = gdelta[b] + slot;
    }
    __syncthreads();
    for (int i = t; i < n; i += 256) stg[gp[i]] = lpak[i];
}

// ---------------- per-bucket counting sort -> ssrc, cnt, off, dinv ----------------
__global__ __launch_bounds__(256) void kb_csr(const unsigned* __restrict__ stg,
                                              const int* __restrict__ bbase,
                                              const int* __restrict__ bhist, int N,
                                              int* __restrict__ ssrc, int* __restrict__ off,
                                              int* __restrict__ cnt, float* __restrict__ dinv) {
    __shared__ int h[256], lcur[256], sc[256];
    int b = blockIdx.x;
    int t = threadIdx.x;
    int s0 = bbase[b], m = bhist[b];
    h[t] = 0;
    __syncthreads();
    for (int i = t; i < m; i += 256) atomicAdd(&h[stg[s0 + i] >> 17], 1);
    __syncthreads();
    int v = h[t];
    sc[t] = v;
    __syncthreads();
    for (int d = 1; d < 256; d <<= 1) {
        int a = (t >= d) ? sc[t - d] : 0;
        __syncthreads();
        sc[t] += a;
        __syncthreads();
    }
    int lb = sc[t] - v;
    lcur[t] = lb;
    int node = (b << BSH) + t;
    if (node < N) {
        off[node] = s0 + lb;
        cnt[node] = v;
        dinv[node] = rsqrtf(1.0f + (float)v);
    }
    __syncthreads();
    for (int i = t; i < m; i += 256) {
        unsigned p = stg[s0 + i];
        int d = p >> 17;
        int r = atomicAdd(&lcur[d], 1);
        ssrc[s0 + r] = (int)(p & 0x1FFFFu);
    }
}

// ---------------- degree counting-sort: perm = nodes ordered by cnt ----------------
__global__ void k_dhist(const int* __restrict__ cnt, int N, int* __restrict__ dh) {
    int i = blockIdx.x * blockDim.x + threadIdx.x;
    if (i < N) atomicAdd(&dh[min(cnt[i], 63)], 1);
}
__global__ void k_dscan(const int* __restrict__ dh, int* __restrict__ dcur) {
    __shared__ int s[64];
    int t = threadIdx.x;
    int v = dh[t];
    s[t] = v;
    __syncthreads();
    for (int d = 1; d < 64; d <<= 1) {
        int a = (t >= d) ? s[t - d] : 0;
        __syncthreads();
        s[t] += a;
        __syncthreads();
    }
    dcur[t] = s[t] - v;  // exclusive
}
__global__ void k_dperm(const int* __restrict__ cnt, int N, int* __restrict__ dcur,
                        int* __restrict__ perm) {
    int i = blockIdx.x * blockDim.x + threadIdx.x;
    if (i < N) {
        int p = atomicAdd(&dcur[min(cnt[i], 63)], 1);
        perm[p] = i;
    }
}

// ---------------- graph boundaries from sorted batch ----------------
__global__ void k_gstart(const int* __restrict__ batch, int N, int G, int* __restrict__ gstart) {
    int i = blockIdx.x * blockDim.x + threadIdx.x;
    if (i >= N) return;
    int b = batch[i];
    int bp = (i == 0) ? -1 : batch[i - 1];
    for (int g = bp + 1; g <= b; ++g) gstart[g] = i;
    if (i == N - 1) {
        for (int g = b + 1; g <= G; ++g) gstart[g] = N;
    }
}

// ---------------- W pre-pack: f32 [K=128][N=128] -> per-fragment bf16 ----------------
__global__ void k_wpre(const float* __restrict__ W, unsigned short* __restrict__ Wpre) {
    int tid = blockIdx.x * 256 + threadIdx.x;  // 2048 threads
    int frag = tid >> 6;
    int l = tid & 63;
    int cf = frag >> 2, ks = frag & 3;
    int col = cf * 16 + (l & 15);
    int k0 = ks * 32 + (l >> 4) * 8;
    unsigned short o[8];
#pragma unroll
    for (int j = 0; j < 8; ++j)
        o[j] = (unsigned short)bf16rne(W[(k0 + j) * 128 + col]);
    *(uint4*)(Wpre + (size_t)tid * 8) = *(const uint4*)o;
}

// ---------------- int8 helpers ----------------
__device__ inline unsigned umax16pair(unsigned d, unsigned cur) {
    unsigned a = d & 0x7FFF7FFFu;          // abs of two bf16 (no NaNs here)
    unsigned lo = a & 0xFFFFu, hi = a >> 16;
    unsigned m = lo > hi ? lo : hi;
    return m > cur ? m : cur;
}
__device__ inline unsigned q8b(float x, float si) {
    return (unsigned)(__float2int_rn(x * si) + 128) & 0xFFu;
}
__device__ inline unsigned pack2(unsigned d0, unsigned d1, float si) {
    float x0 = bfl(d0), x1 = bfh(d0), x2 = bfl(d1), x3 = bfh(d1);
    return q8b(x0, si) | (q8b(x1, si) << 8) | (q8b(x2, si) << 16) | (q8b(x3, si) << 24);
}

// ---------------- MFMA GEMM -> int8 row-scaled table ----------------
// Q8[row][c] = biased uint8 of (X@W)[row][c]*dinv[row];  srow[row] = rowmax/127
template <bool BF16IN>
__global__ __launch_bounds__(256, 4) void k_gemm_mfma(const void* __restrict__ Xv,
                                                      const unsigned short* __restrict__ Wpre,
                                                      const float* __restrict__ dinv,
                                                      unsigned char* __restrict__ Q8,
                                                      float* __restrict__ srow, int N) {
    __shared__ __align__(16) unsigned short sA[128 * 128];  // 32 KB
    __shared__ unsigned sMaxH[256];
    int t = threadIdx.x;
    int r0 = blockIdx.x * 128;
    int rows = N - r0; if (rows > 128) rows = 128;

    if constexpr (!BF16IN) {
        const float4* X4 = (const float4*)((const float*)Xv + (size_t)r0 * 128);
#pragma unroll
        for (int j = 0; j < 16; ++j) {
            int f = j * 256 + t;
            int row = f >> 5, q = f & 31;
            float4 v = make_float4(0.f, 0.f, 0.f, 0.f);
            if (row < rows) v = X4[f];
            unsigned lo = bf16rne(v.x) | (bf16rne(v.y) << 16);
            unsigned hi = bf16rne(v.z) | (bf16rne(v.w) << 16);
            int byte = row * 256 + SWZ(row, q * 8);
            *(uint2*)((char*)sA + byte) = make_uint2(lo, hi);
        }
    } else {
        const uint4* X4 = (const uint4*)((const unsigned short*)Xv + (size_t)r0 * 128);
#pragma unroll
        for (int j = 0; j < 8; ++j) {
            int f = j * 256 + t;
            int row = f >> 4, q = f & 15;
            uint4 v = make_uint4(0u, 0u, 0u, 0u);
            if (row < rows) v = X4[f];
            int byte = row * 256 + SWZ(row, q * 16);
            *(uint4*)((char*)sA + byte) = v;
        }
    }
    __syncthreads();

    int w = t >> 6, l = t & 63;
    int wr = (w >> 1) * 64, wc = (w & 1) * 64;
    int lr = l & 15, kc = l >> 4;

    f32x4 acc[4][4] = {};
    for (int ks = 0; ks < 4; ++ks) {
        bf16x8 a[4], b[4];
#pragma unroll
        for (int m = 0; m < 4; ++m) {
            int row = wr + m * 16 + lr;
            int byte = row * 256 + SWZ(row, ks * 64 + kc * 16);
            a[m] = *(const bf16x8*)((const char*)sA + byte);
        }
#pragma unroll
        for (int n = 0; n < 4; ++n) {
            int cf = (wc >> 4) + n;
            b[n] = *(const bf16x8*)(Wpre + ((size_t)((cf * 4 + ks) * 64 + l) * 8));
        }
#pragma unroll
        for (int m = 0; m < 4; ++m)
#pragma unroll
            for (int n = 0; n < 4; ++n)
                acc[m][n] = __builtin_amdgcn_mfma_f32_16x16x32_bf16(a[m], b[n], acc[m][n], 0, 0, 0);
    }
    __syncthreads();

    // phase 1: x dinv -> bf16 tile in LDS (linear)
#pragma unroll
    for (int m = 0; m < 4; ++m) {
        int rbase = wr + m * 16 + kc * 4;
#pragma unroll
        for (int r = 0; r < 4; ++r) {
            int row = rbase + r;
            float dv = (r0 + row < N) ? dinv[r0 + row] : 0.f;
#pragma unroll
            for (int n = 0; n < 4; ++n) {
                int col = wc + n * 16 + lr;
                sA[row * 128 + col] = (unsigned short)bf16rne(acc[m][n][r] * dv);
            }
        }
    }
    __syncthreads();

    // phase 2: rowmax + int8 quantize. thread t: row r=t>>1, half hh=t&1 (64 cols)
    {
        int r = t >> 1, hh = t & 1;
        const uint4* rowp = (const uint4*)(sA + r * 128 + hh * 64);
        uint4 wreg[8];
#pragma unroll
        for (int j = 0; j < 8; ++j) wreg[j] = rowp[j];
        unsigned mb = 0;
#pragma unroll
        for (int j = 0; j < 8; ++j) {
            mb = umax16pair(wreg[j].x, mb);
            mb = umax16pair(wreg[j].y, mb);
            mb = umax16pair(wreg[j].z, mb);
            mb = umax16pair(wreg[j].w, mb);
        }
        sMaxH[r * 2 + hh] = mb;
        __syncthreads();
        unsigned m0 = sMaxH[r * 2], m1 = sMaxH[r * 2 + 1];
        unsigned m16 = m0 > m1 ? m0 : m1;
        float mv = __uint_as_float(m16 << 16);
        float si = (mv > 0.f) ? 127.0f / mv : 0.0f;
        if (hh == 0 && r0 + r < N) srow[r0 + r] = mv * (1.0f / 127.0f);
        if (r0 + r < N) {
            unsigned q[16];
#pragma unroll
            for (int j = 0; j < 8; ++j) {
                q[2 * j]     = pack2(wreg[j].x, wreg[j].y, si);
                q[2 * j + 1] = pack2(wreg[j].z, wreg[j].w, si);
            }
            uint4* qo = (uint4*)(Q8 + (size_t)(r0 + r) * 128 + hh * 64);
            qo[0] = make_uint4(q[0], q[1], q[2], q[3]);
            qo[1] = make_uint4(q[4], q[5], q[6], q[7]);
            qo[2] = make_uint4(q[8], q[9], q[10], q[11]);
            qo[3] = make_uint4(q[12], q[13], q[14], q[15]);
        }
    }
}

// ---------------- aggregation: eighth-wave per node, int8 table ----------------
// 8 lanes x uint4 = full 128B int8 row per load; 8 chains/wave; degree-sorted
// node order via perm to equalize the 8 streams' trip counts.
#define ACCU(u, s, A, B, C, D) {                      \
    A = fmaf(s, (float)((u) & 0xFFu), A);             \
    B = fmaf(s, (float)(((u) >> 8) & 0xFFu), B);      \
    C = fmaf(s, (float)(((u) >> 16) & 0xFFu), C);     \
    D = fmaf(s, (float)((u) >> 24), D); }
#define ACCROW8(R, S) { float _s = (S); ssum += _s;   \
    ACCU(R.x, _s, a0, a1, a2, a3)                     \
    ACCU(R.y, _s, a4, a5, a6, a7)                     \
    ACCU(R.z, _s, a8, a9, a10, a11)                   \
    ACCU(R.w, _s, a12, a13, a14, a15) }

__global__ __launch_bounds__(256) void k_agg8(const unsigned char* __restrict__ Q8,
                                              const float* __restrict__ srow,
                                              const int* __restrict__ off,
                                              const int* __restrict__ cnt,
                                              const int* __restrict__ ssrc,
                                              const int* __restrict__ perm,
                                              const float* __restrict__ dinv,
                                              const float* __restrict__ b,
                                              unsigned* __restrict__ OUTB, int N) {
    int slot = (blockIdx.x * blockDim.x + threadIdx.x) >> 3;
    if (slot >= N) return;
    int j = threadIdx.x & 7;            // 16 cols: j*16 .. j*16+15
    int v = perm[slot];

    float a0 = 0.f, a1 = 0.f, a2 = 0.f, a3 = 0.f, a4 = 0.f, a5 = 0.f, a6 = 0.f, a7 = 0.f;
    float a8 = 0.f, a9 = 0.f, a10 = 0.f, a11 = 0.f, a12 = 0.f, a13 = 0.f, a14 = 0.f, a15 = 0.f;
    float ssum = 0.f;

    {   // self term
        uint4 r = *(const uint4*)(Q8 + (size_t)v * 128 + j * 16);
        float s = srow[v];
        ACCROW8(r, s)
    }
    int i = off[v], e = i + cnt[v];
    for (; i + 4 <= e; i += 4) {
        int4 uu = *(const int4*)(ssrc + i);
        uint4 r0 = *(const uint4*)(Q8 + (size_t)uu.x * 128 + j * 16);
        uint4 r1 = *(const uint4*)(Q8 + (size_t)uu.y * 128 + j * 16);
        uint4 r2 = *(const uint4*)(Q8 + (size_t)uu.z * 128 + j * 16);
        uint4 r3 = *(const uint4*)(Q8 + (size_t)uu.w * 128 + j * 16);
        float s0 = srow[uu.x], s1 = srow[uu.y], s2 = srow[uu.z], s3 = srow[uu.w];
        ACCROW8(r0, s0) ACCROW8(r1, s1) ACCROW8(r2, s2) ACCROW8(r3, s3)
    }
    for (; i < e; ++i) {
        int u = ssrc[i];
        uint4 r = *(const uint4*)(Q8 + (size_t)u * 128 + j * 16);
        float s = srow[u];
        ACCROW8(r, s)
    }

    float dv = dinv[v];
    float corr = 128.f * ssum;
    const float4* B4 = (const float4*)(b + j * 16);
    float4 bb0 = B4[0], bb1 = B4[1], bb2 = B4[2], bb3 = B4[3];
    float o0  = fmaxf((a0  - corr) * dv + bb0.x, 0.f);
    float o1  = fmaxf((a1  - corr) * dv + bb0.y, 0.f);
    float o2  = fmaxf((a2  - corr) * dv + bb0.z, 0.f);
    float o3  = fmaxf((a3  - corr) * dv + bb0.w, 0.f);
    float o4  = fmaxf((a4  - corr) * dv + bb1.x, 0.f);
    float o5  = fmaxf((a5  - corr) * dv + bb1.y, 0.f);
    float o6  = fmaxf((a6  - corr) * dv + bb1.z, 0.f);
    float o7  = fmaxf((a7  - corr) * dv + bb1.w, 0.f);
    float o8  = fmaxf((a8  - corr) * dv + bb2.x, 0.f);
    float o9  = fmaxf((a9  - corr) * dv + bb2.y, 0.f);
    float o10 = fmaxf((a10 - corr) * dv + bb2.z, 0.f);
    float o11 = fmaxf((a11 - corr) * dv + bb2.w, 0.f);
    float o12 = fmaxf((a12 - corr) * dv + bb3.x, 0.f);
    float o13 = fmaxf((a13 - corr) * dv + bb3.y, 0.f);
    float o14 = fmaxf((a14 - corr) * dv + bb3.z, 0.f);
    float o15 = fmaxf((a15 - corr) * dv + bb3.w, 0.f);

    uint4 w0, w1;
    w0.x = bf16rne(o0)  | (bf16rne(o1)  << 16);
    w0.y = bf16rne(o2)  | (bf16rne(o3)  << 16);
    w0.z = bf16rne(o4)  | (bf16rne(o5)  << 16);
    w0.w = bf16rne(o6)  | (bf16rne(o7)  << 16);
    w1.x = bf16rne(o8)  | (bf16rne(o9)  << 16);
    w1.y = bf16rne(o10) | (bf16rne(o11) << 16);
    w1.z = bf16rne(o12) | (bf16rne(o13) << 16);
    w1.w = bf16rne(o14) | (bf16rne(o15) << 16);
    uint4* orow = (uint4*)OUTB + (size_t)v * 16 + j * 2;
    orow[0] = w0;
    orow[1] = w1;
}

// ---------------- fused segmented-mean pool + linear head (bf16 input) ----------------
__global__ __launch_bounds__(256) void k_pool_head(const unsigned* __restrict__ H2,
                                                   const int* __restrict__ gstart,
                                                   const float* __restrict__ Wlin,
                                                   const float* __restrict__ blin,
                                                   float* __restrict__ out, int G) {
    __shared__ float2 stmp[256];
    __shared__ float sp[128];
    int g = blockIdx.x;
    int t = threadIdx.x;
    int p = t & 63, quarter = t >> 6;
    int s = gstart[g], e = gstart[g + 1];
    float2 acc = make_float2(0.f, 0.f);
    for (int i = s + quarter; i < e; i += 4) {
        unsigned u = H2[(size_t)i * 64 + p];
        acc.x += bfl(u);
        acc.y += bfh(u);
    }
    stmp[t] = acc;
    __syncthreads();
    if (t < 64) {
        float2 a = stmp[t];
        a.x += stmp[t + 64].x + stmp[t + 128].x + stmp[t + 192].x;
        a.y += stmp[t + 64].y + stmp[t + 128].y + stmp[t + 192].y;
        float inv = 1.0f / fmaxf((float)(e - s), 1.0f);
        sp[2 * t] = a.x * inv;
        sp[2 * t + 1] = a.y * inv;
    }
    __syncthreads();
    if (t < 2) {
        float a = 0.0f;
        for (int j = 0; j < 128; ++j) a += sp[j] * Wlin[j * 2 + t];
        out[g * 2 + t] = a + blin[t];
    }
}

extern "C" void kernel_launch(void* const* d_in, const int* in_sizes, int n_in,
                              void* d_out, int out_size, void* d_ws, size_t ws_size,
                              hipStream_t stream) {
    const float* x     = (const float*)d_in[0];
    const int*   ei    = (const int*)d_in[1];   // [2,E]
    const int*   batch = (const int*)d_in[2];   // [N]
    const float* W1    = (const float*)d_in[4];
    const float* b1    = (const float*)d_in[5];
    const float* W2    = (const float*)d_in[6];
    const float* b2    = (const float*)d_in[7];
    const float* Wlin  = (const float*)d_in[8];
    const float* blin  = (const float*)d_in[9];
    float* out = (float*)d_out;

    const int N = in_sizes[0] / FEAT;
    const int E = in_sizes[1] / 2;
    const int G = GRAPHS;
    const int NB = (N + (1 << BSH) - 1) >> BSH;
    const int* src = ei;
    const int* dst = ei + E;

    // workspace carve-up
    char* ws = (char*)d_ws;
    unsigned char* q8 = (unsigned char*)ws;                // N*128 int8 table
    float* srow = (float*)(q8 + (size_t)N * FEAT);         // N
    unsigned short* hact = (unsigned short*)(srow + N);    // N*128 bf16 activations
    int*   ssrc = (int*)(hact + (size_t)N * FEAT);         // E
    unsigned* stg = (unsigned*)(ssrc + E);                 // E
    int*   off  = (int*)(stg + E);                         // N
    int*   cnt  = off + N;                                 // N
    float* dinv = (float*)(cnt + N);                       // N
    int*   perm = (int*)(dinv + N);                        // N
    int*   bhist = perm + N;                               // MAXNB
    int*   bbase = bhist + MAXNB;                          // MAXNB
    int*   bcur  = bbase + MAXNB;                          // MAXNB
    int*   dh    = bcur + MAXNB;                           // 64
    int*   dcur  = dh + 64;                                // 64
    int*   gstart = dcur + 64;                             // G+1
    unsigned short* wpre1 = (unsigned short*)(gstart + G + 2); // 16384
    unsigned short* wpre2 = wpre1 + 16384;                 // 16384

    const int nb = (N + 255) / 256;
    const int nch = (E + CH - 1) / CH;
    const int ngb = (N + 127) / 128;

    hipMemsetAsync(bhist, 0, (size_t)NB * sizeof(int), stream);
    hipMemsetAsync(dh, 0, 64 * sizeof(int), stream);

    // W pre-pack (independent)
    k_wpre<<<8, 256, 0, stream>>>(W1, wpre1);
    k_wpre<<<8, 256, 0, stream>>>(W2, wpre2);

    // CSR build
    kb_hist<<<256, 256, 0, stream>>>(dst, E, NB, bhist);
    kb_scan<<<1, 512, 0, stream>>>(bhist, NB, bbase, bcur);
    kb_group<<<nch, 256, 0, stream>>>(src, dst, E, NB, bcur, stg);
    kb_csr<<<NB, 256, 0, stream>>>(stg, bbase, bhist, N, ssrc, off, cnt, dinv);

    // degree sort (needs cnt)
    k_dhist<<<nb, 256, 0, stream>>>(cnt, N, dh);
    k_dscan<<<1, 64, 0, stream>>>(dh, dcur);
    k_dperm<<<nb, 256, 0, stream>>>(cnt, N, dcur, perm);

    // graph boundaries
    k_gstart<<<nb, 256, 0, stream>>>(batch, N, G, gstart);

    // layer 1
    k_gemm_mfma<false><<<ngb, 256, 0, stream>>>(x, wpre1, dinv, q8, srow, N);
    k_agg8<<<(N * 8 + 255) / 256, 256, 0, stream>>>(q8, srow, off, cnt, ssrc, perm, dinv, b1, (unsigned*)hact, N);
    // layer 2
    k_gemm_mfma<true><<<ngb, 256, 0, stream>>>(hact, wpre2, dinv, q8, srow, N);
    k_agg8<<<(N * 8 + 255) / 256, 256, 0, stream>>>(q8, srow, off, cnt, ssrc, perm, dinv, b2, (unsigned*)hact, N);

    // fused pool + head
    k_pool_head<<<G, 256, 0, stream>>>((const unsigned*)hact, gstart, Wlin, blin, out, G);
}

// Round 9
// 318.310 us; speedup vs baseline: 2.6593x; 2.6593x over previous
//
#include <hip/hip_runtime.h>
#include <hip/hip_bf16.h>

// GCN: h1 = relu(gcnconv(x,W1,b1)); h2 = relu(gcnconv(h1,W2,b2));
// pooled = segment_mean(h2, batch); out = pooled@Wlin + blin
//
// R9: R8 minus the degree sort (k_dhist/k_dperm were 100K global atomics on
// 64 addresses -> 520us same-address serialization, the R1 pathology again).
// Keep int8 table + eighth-wave-per-node agg (2 lines/edge, 8 chains/wave),
// natural node order.

#define FEAT 128
#define GRAPHS 256
#define CH 2048
#define BSH 8
#define MAXNB 512

typedef short bf16x8 __attribute__((ext_vector_type(8)));
typedef float f32x4 __attribute__((ext_vector_type(4)));

__device__ inline unsigned bf16rne(float f) {
    unsigned u = __float_as_uint(f);
    return (u + 0x7FFFu + ((u >> 16) & 1u)) >> 16;
}
__device__ inline float bfl(unsigned u) { return __uint_as_float(u << 16); }
__device__ inline float bfh(unsigned u) { return __uint_as_float(u & 0xFFFF0000u); }

#define SWZ(row, kbyte) ((kbyte) ^ (((row) & 7) << 4))

// ---------------- bucket histogram ----------------
__global__ __launch_bounds__(256) void kb_hist(const int* __restrict__ dst, int E, int NB,
                                               int* __restrict__ bhist) {
    __shared__ int h[MAXNB];
    for (int i = threadIdx.x; i < NB; i += 256) h[i] = 0;
    __syncthreads();
    int stride = gridDim.x * 256;
    for (int i = blockIdx.x * 256 + threadIdx.x; i < E; i += stride)
        atomicAdd(&h[dst[i] >> BSH], 1);
    __syncthreads();
    for (int i = threadIdx.x; i < NB; i += 256)
        if (h[i]) atomicAdd(&bhist[i], h[i]);
}

// ---------------- bucket base scan ----------------
__global__ void kb_scan(const int* __restrict__ bhist, int NB,
                        int* __restrict__ bbase, int* __restrict__ bcur) {
    __shared__ int s[512];
    int t = threadIdx.x;
    int v = (t < NB) ? bhist[t] : 0;
    s[t] = v;
    __syncthreads();
    for (int d = 1; d < 512; d <<= 1) {
        int a = (t >= d) ? s[t - d] : 0;
        __syncthreads();
        s[t] += a;
        __syncthreads();
    }
    if (t < NB) { int e = s[t] - v; bbase[t] = e; bcur[t] = e; }
}

// ---------------- group edges by bucket into staging (packed) ----------------
__global__ __launch_bounds__(256) void kb_group(const int* __restrict__ src,
                                                const int* __restrict__ dst, int E, int NB,
                                                int* __restrict__ bcur,
                                                unsigned* __restrict__ stg) {
    __shared__ int lhist[MAXNB], lcur[MAXNB], gdelta[MAXNB], sc[512];
    __shared__ unsigned lpak[CH];
    __shared__ int gp[CH];
    int t = threadIdx.x;
    int base = blockIdx.x * CH;
    int n = E - base; if (n > CH) n = CH;

    for (int i = t; i < NB; i += 256) lhist[i] = 0;
    __syncthreads();

    unsigned pk[8]; int bk[8]; int nl = 0;
#pragma unroll
    for (int j = 0; j < 8; ++j) {
        int k = j * 256 + t;
        if (k < n) {
            int d = dst[base + k];
            int sv = src[base + k];
            int b = d >> BSH;
            pk[nl] = ((unsigned)(d & ((1 << BSH) - 1)) << 17) | (unsigned)sv;
            bk[nl] = b; nl++;
            atomicAdd(&lhist[b], 1);
        }
    }
    __syncthreads();

    for (int i = t; i < 512; i += 256) sc[i] = (i < NB) ? lhist[i] : 0;
    __syncthreads();
    for (int d = 1; d < 512; d <<= 1) {
        int a0 = (t >= d) ? sc[t - d] : 0;
        int a1 = sc[t + 256 - d];
        __syncthreads();
        sc[t] += a0; sc[t + 256] += a1;
        __syncthreads();
    }
    for (int i = t; i < NB; i += 256) {
        int c = lhist[i];
        int lb = sc[i] - c;
        lcur[i] = lb;
        int g = c ? atomicAdd(&bcur[i], c) : 0;
        gdelta[i] = g - lb;
    }
    __syncthreads();

    for (int j = 0; j < nl; ++j) {
        int b = bk[j];
        int slot = atomicAdd(&lcur[b], 1);
        lpak[slot] = pk[j];
        gp[slot] = gdelta[b] + slot;
    }
    __syncthreads();
    for (int i = t; i < n; i += 256) stg[gp[i]] = lpak[i];
}

// ---------------- per-bucket counting sort -> ssrc, cnt, off, dinv ----------------
__global__ __launch_bounds__(256) void kb_csr(const unsigned* __restrict__ stg,
                                              const int* __restrict__ bbase,
                                              const int* __restrict__ bhist, int N,
                                              int* __restrict__ ssrc, int* __restrict__ off,
                                              int* __restrict__ cnt, float* __restrict__ dinv) {
    __shared__ int h[256], lcur[256], sc[256];
    int b = blockIdx.x;
    int t = threadIdx.x;
    int s0 = bbase[b], m = bhist[b];
    h[t] = 0;
    __syncthreads();
    for (int i = t; i < m; i += 256) atomicAdd(&h[stg[s0 + i] >> 17], 1);
    __syncthreads();
    int v = h[t];
    sc[t] = v;
    __syncthreads();
    for (int d = 1; d < 256; d <<= 1) {
        int a = (t >= d) ? sc[t - d] : 0;
        __syncthreads();
        sc[t] += a;
        __syncthreads();
    }
    int lb = sc[t] - v;
    lcur[t] = lb;
    int node = (b << BSH) + t;
    if (node < N) {
        off[node] = s0 + lb;
        cnt[node] = v;
        dinv[node] = rsqrtf(1.0f + (float)v);
    }
    __syncthreads();
    for (int i = t; i < m; i += 256) {
        unsigned p = stg[s0 + i];
        int d = p >> 17;
        int r = atomicAdd(&lcur[d], 1);
        ssrc[s0 + r] = (int)(p & 0x1FFFFu);
    }
}

// ---------------- graph boundaries from sorted batch ----------------
__global__ void k_gstart(const int* __restrict__ batch, int N, int G, int* __restrict__ gstart) {
    int i = blockIdx.x * blockDim.x + threadIdx.x;
    if (i >= N) return;
    int b = batch[i];
    int bp = (i == 0) ? -1 : batch[i - 1];
    for (int g = bp + 1; g <= b; ++g) gstart[g] = i;
    if (i == N - 1) {
        for (int g = b + 1; g <= G; ++g) gstart[g] = N;
    }
}

// ---------------- W pre-pack: f32 [K=128][N=128] -> per-fragment bf16 ----------------
__global__ void k_wpre(const float* __restrict__ W, unsigned short* __restrict__ Wpre) {
    int tid = blockIdx.x * 256 + threadIdx.x;  // 2048 threads
    int frag = tid >> 6;
    int l = tid & 63;
    int cf = frag >> 2, ks = frag & 3;
    int col = cf * 16 + (l & 15);
    int k0 = ks * 32 + (l >> 4) * 8;
    unsigned short o[8];
#pragma unroll
    for (int j = 0; j < 8; ++j)
        o[j] = (unsigned short)bf16rne(W[(k0 + j) * 128 + col]);
    *(uint4*)(Wpre + (size_t)tid * 8) = *(const uint4*)o;
}

// ---------------- int8 helpers ----------------
__device__ inline unsigned umax16pair(unsigned d, unsigned cur) {
    unsigned a = d & 0x7FFF7FFFu;          // abs of two bf16 (no NaNs here)
    unsigned lo = a & 0xFFFFu, hi = a >> 16;
    unsigned m = lo > hi ? lo : hi;
    return m > cur ? m : cur;
}
__device__ inline unsigned q8b(float x, float si) {
    return (unsigned)(__float2int_rn(x * si) + 128) & 0xFFu;
}
__device__ inline unsigned pack2(unsigned d0, unsigned d1, float si) {
    float x0 = bfl(d0), x1 = bfh(d0), x2 = bfl(d1), x3 = bfh(d1);
    return q8b(x0, si) | (q8b(x1, si) << 8) | (q8b(x2, si) << 16) | (q8b(x3, si) << 24);
}

// ---------------- MFMA GEMM -> int8 row-scaled table ----------------
// Q8[row][c] = biased uint8 of (X@W)[row][c]*dinv[row];  srow[row] = rowmax/127
template <bool BF16IN>
__global__ __launch_bounds__(256, 4) void k_gemm_mfma(const void* __restrict__ Xv,
                                                      const unsigned short* __restrict__ Wpre,
                                                      const float* __restrict__ dinv,
                                                      unsigned char* __restrict__ Q8,
                                                      float* __restrict__ srow, int N) {
    __shared__ __align__(16) unsigned short sA[128 * 128];  // 32 KB
    __shared__ unsigned sMaxH[256];
    int t = threadIdx.x;
    int r0 = blockIdx.x * 128;
    int rows = N - r0; if (rows > 128) rows = 128;

    if constexpr (!BF16IN) {
        const float4* X4 = (const float4*)((const float*)Xv + (size_t)r0 * 128);
#pragma unroll
        for (int j = 0; j < 16; ++j) {
            int f = j * 256 + t;
            int row = f >> 5, q = f & 31;
            float4 v = make_float4(0.f, 0.f, 0.f, 0.f);
            if (row < rows) v = X4[f];
            unsigned lo = bf16rne(v.x) | (bf16rne(v.y) << 16);
            unsigned hi = bf16rne(v.z) | (bf16rne(v.w) << 16);
            int byte = row * 256 + SWZ(row, q * 8);
            *(uint2*)((char*)sA + byte) = make_uint2(lo, hi);
        }
    } else {
        const uint4* X4 = (const uint4*)((const unsigned short*)Xv + (size_t)r0 * 128);
#pragma unroll
        for (int j = 0; j < 8; ++j) {
            int f = j * 256 + t;
            int row = f >> 4, q = f & 15;
            uint4 v = make_uint4(0u, 0u, 0u, 0u);
            if (row < rows) v = X4[f];
            int byte = row * 256 + SWZ(row, q * 16);
            *(uint4*)((char*)sA + byte) = v;
        }
    }
    __syncthreads();

    int w = t >> 6, l = t & 63;
    int wr = (w >> 1) * 64, wc = (w & 1) * 64;
    int lr = l & 15, kc = l >> 4;

    f32x4 acc[4][4] = {};
    for (int ks = 0; ks < 4; ++ks) {
        bf16x8 a[4], b[4];
#pragma unroll
        for (int m = 0; m < 4; ++m) {
            int row = wr + m * 16 + lr;
            int byte = row * 256 + SWZ(row, ks * 64 + kc * 16);
            a[m] = *(const bf16x8*)((const char*)sA + byte);
        }
#pragma unroll
        for (int n = 0; n < 4; ++n) {
            int cf = (wc >> 4) + n;
            b[n] = *(const bf16x8*)(Wpre + ((size_t)((cf * 4 + ks) * 64 + l) * 8));
        }
#pragma unroll
        for (int m = 0; m < 4; ++m)
#pragma unroll
            for (int n = 0; n < 4; ++n)
                acc[m][n] = __builtin_amdgcn_mfma_f32_16x16x32_bf16(a[m], b[n], acc[m][n], 0, 0, 0);
    }
    __syncthreads();

    // phase 1: x dinv -> bf16 tile in LDS (linear)
#pragma unroll
    for (int m = 0; m < 4; ++m) {
        int rbase = wr + m * 16 + kc * 4;
#pragma unroll
        for (int r = 0; r < 4; ++r) {
            int row = rbase + r;
            float dv = (r0 + row < N) ? dinv[r0 + row] : 0.f;
#pragma unroll
            for (int n = 0; n < 4; ++n) {
                int col = wc + n * 16 + lr;
                sA[row * 128 + col] = (unsigned short)bf16rne(acc[m][n][r] * dv);
            }
        }
    }
    __syncthreads();

    // phase 2: rowmax + int8 quantize. thread t: row r=t>>1, half hh=t&1 (64 cols)
    {
        int r = t >> 1, hh = t & 1;
        const uint4* rowp = (const uint4*)(sA + r * 128 + hh * 64);
        uint4 wreg[8];
#pragma unroll
        for (int j = 0; j < 8; ++j) wreg[j] = rowp[j];
        unsigned mb = 0;
#pragma unroll
        for (int j = 0; j < 8; ++j) {
            mb = umax16pair(wreg[j].x, mb);
            mb = umax16pair(wreg[j].y, mb);
            mb = umax16pair(wreg[j].z, mb);
            mb = umax16pair(wreg[j].w, mb);
        }
        sMaxH[r * 2 + hh] = mb;
        __syncthreads();
        unsigned m0 = sMaxH[r * 2], m1 = sMaxH[r * 2 + 1];
        unsigned m16 = m0 > m1 ? m0 : m1;
        float mv = __uint_as_float(m16 << 16);
        float si = (mv > 0.f) ? 127.0f / mv : 0.0f;
        if (hh == 0 && r0 + r < N) srow[r0 + r] = mv * (1.0f / 127.0f);
        if (r0 + r < N) {
            unsigned q[16];
#pragma unroll
            for (int j = 0; j < 8; ++j) {
                q[2 * j]     = pack2(wreg[j].x, wreg[j].y, si);
                q[2 * j + 1] = pack2(wreg[j].z, wreg[j].w, si);
            }
            uint4* qo = (uint4*)(Q8 + (size_t)(r0 + r) * 128 + hh * 64);
            qo[0] = make_uint4(q[0], q[1], q[2], q[3]);
            qo[1] = make_uint4(q[4], q[5], q[6], q[7]);
            qo[2] = make_uint4(q[8], q[9], q[10], q[11]);
            qo[3] = make_uint4(q[12], q[13], q[14], q[15]);
        }
    }
}

// ---------------- aggregation: eighth-wave per node, int8 table ----------------
// 8 lanes x uint4 = full 128B int8 row per load; 8 chains/wave; natural order.
#define ACCU(u, s, A, B, C, D) {                      \
    A = fmaf(s, (float)((u) & 0xFFu), A);             \
    B = fmaf(s, (float)(((u) >> 8) & 0xFFu), B);      \
    C = fmaf(s, (float)(((u) >> 16) & 0xFFu), C);     \
    D = fmaf(s, (float)((u) >> 24), D); }
#define ACCROW8(R, S) { float _s = (S); ssum += _s;   \
    ACCU(R.x, _s, a0, a1, a2, a3)                     \
    ACCU(R.y, _s, a4, a5, a6, a7)                     \
    ACCU(R.z, _s, a8, a9, a10, a11)                   \
    ACCU(R.w, _s, a12, a13, a14, a15) }

__global__ __launch_bounds__(256) void k_agg8(const unsigned char* __restrict__ Q8,
                                              const float* __restrict__ srow,
                                              const int* __restrict__ off,
                                              const int* __restrict__ cnt,
                                              const int* __restrict__ ssrc,
                                              const float* __restrict__ dinv,
                                              const float* __restrict__ b,
                                              unsigned* __restrict__ OUTB, int N) {
    int v = (blockIdx.x * blockDim.x + threadIdx.x) >> 3;
    if (v >= N) return;
    int j = threadIdx.x & 7;            // 16 cols: j*16 .. j*16+15

    float a0 = 0.f, a1 = 0.f, a2 = 0.f, a3 = 0.f, a4 = 0.f, a5 = 0.f, a6 = 0.f, a7 = 0.f;
    float a8 = 0.f, a9 = 0.f, a10 = 0.f, a11 = 0.f, a12 = 0.f, a13 = 0.f, a14 = 0.f, a15 = 0.f;
    float ssum = 0.f;

    {   // self term
        uint4 r = *(const uint4*)(Q8 + (size_t)v * 128 + j * 16);
        float s = srow[v];
        ACCROW8(r, s)
    }
    int i = off[v], e = i + cnt[v];
    for (; i + 4 <= e; i += 4) {
        int4 uu = *(const int4*)(ssrc + i);
        uint4 r0 = *(const uint4*)(Q8 + (size_t)uu.x * 128 + j * 16);
        uint4 r1 = *(const uint4*)(Q8 + (size_t)uu.y * 128 + j * 16);
        uint4 r2 = *(const uint4*)(Q8 + (size_t)uu.z * 128 + j * 16);
        uint4 r3 = *(const uint4*)(Q8 + (size_t)uu.w * 128 + j * 16);
        float s0 = srow[uu.x], s1 = srow[uu.y], s2 = srow[uu.z], s3 = srow[uu.w];
        ACCROW8(r0, s0) ACCROW8(r1, s1) ACCROW8(r2, s2) ACCROW8(r3, s3)
    }
    for (; i < e; ++i) {
        int u = ssrc[i];
        uint4 r = *(const uint4*)(Q8 + (size_t)u * 128 + j * 16);
        float s = srow[u];
        ACCROW8(r, s)
    }

    float dv = dinv[v];
    float corr = 128.f * ssum;
    const float4* B4 = (const float4*)(b + j * 16);
    float4 bb0 = B4[0], bb1 = B4[1], bb2 = B4[2], bb3 = B4[3];
    float o0  = fmaxf((a0  - corr) * dv + bb0.x, 0.f);
    float o1  = fmaxf((a1  - corr) * dv + bb0.y, 0.f);
    float o2  = fmaxf((a2  - corr) * dv + bb0.z, 0.f);
    float o3  = fmaxf((a3  - corr) * dv + bb0.w, 0.f);
    float o4  = fmaxf((a4  - corr) * dv + bb1.x, 0.f);
    float o5  = fmaxf((a5  - corr) * dv + bb1.y, 0.f);
    float o6  = fmaxf((a6  - corr) * dv + bb1.z, 0.f);
    float o7  = fmaxf((a7  - corr) * dv + bb1.w, 0.f);
    float o8  = fmaxf((a8  - corr) * dv + bb2.x, 0.f);
    float o9  = fmaxf((a9  - corr) * dv + bb2.y, 0.f);
    float o10 = fmaxf((a10 - corr) * dv + bb2.z, 0.f);
    float o11 = fmaxf((a11 - corr) * dv + bb2.w, 0.f);
    float o12 = fmaxf((a12 - corr) * dv + bb3.x, 0.f);
    float o13 = fmaxf((a13 - corr) * dv + bb3.y, 0.f);
    float o14 = fmaxf((a14 - corr) * dv + bb3.z, 0.f);
    float o15 = fmaxf((a15 - corr) * dv + bb3.w, 0.f);

    uint4 w0, w1;
    w0.x = bf16rne(o0)  | (bf16rne(o1)  << 16);
    w0.y = bf16rne(o2)  | (bf16rne(o3)  << 16);
    w0.z = bf16rne(o4)  | (bf16rne(o5)  << 16);
    w0.w = bf16rne(o6)  | (bf16rne(o7)  << 16);
    w1.x = bf16rne(o8)  | (bf16rne(o9)  << 16);
    w1.y = bf16rne(o10) | (bf16rne(o11) << 16);
    w1.z = bf16rne(o12) | (bf16rne(o13) << 16);
    w1.w = bf16rne(o14) | (bf16rne(o15) << 16);
    uint4* orow = (uint4*)OUTB + (size_t)v * 16 + j * 2;
    orow[0] = w0;
    orow[1] = w1;
}

// ---------------- fused segmented-mean pool + linear head (bf16 input) ----------------
__global__ __launch_bounds__(256) void k_pool_head(const unsigned* __restrict__ H2,
                                                   const int* __restrict__ gstart,
                                                   const float* __restrict__ Wlin,
                                                   const float* __restrict__ blin,
                                                   float* __restrict__ out, int G) {
    __shared__ float2 stmp[256];
    __shared__ float sp[128];
    int g = blockIdx.x;
    int t = threadIdx.x;
    int p = t & 63, quarter = t >> 6;
    int s = gstart[g], e = gstart[g + 1];
    float2 acc = make_float2(0.f, 0.f);
    for (int i = s + quarter; i < e; i += 4) {
        unsigned u = H2[(size_t)i * 64 + p];
        acc.x += bfl(u);
        acc.y += bfh(u);
    }
    stmp[t] = acc;
    __syncthreads();
    if (t < 64) {
        float2 a = stmp[t];
        a.x += stmp[t + 64].x + stmp[t + 128].x + stmp[t + 192].x;
        a.y += stmp[t + 64].y + stmp[t + 128].y + stmp[t + 192].y;
        float inv = 1.0f / fmaxf((float)(e - s), 1.0f);
        sp[2 * t] = a.x * inv;
        sp[2 * t + 1] = a.y * inv;
    }
    __syncthreads();
    if (t < 2) {
        float a = 0.0f;
        for (int j = 0; j < 128; ++j) a += sp[j] * Wlin[j * 2 + t];
        out[g * 2 + t] = a + blin[t];
    }
}

extern "C" void kernel_launch(void* const* d_in, const int* in_sizes, int n_in,
                              void* d_out, int out_size, void* d_ws, size_t ws_size,
                              hipStream_t stream) {
    const float* x     = (const float*)d_in[0];
    const int*   ei    = (const int*)d_in[1];   // [2,E]
    const int*   batch = (const int*)d_in[2];   // [N]
    const float* W1    = (const float*)d_in[4];
    const float* b1    = (const float*)d_in[5];
    const float* W2    = (const float*)d_in[6];
    const float* b2    = (const float*)d_in[7];
    const float* Wlin  = (const float*)d_in[8];
    const float* blin  = (const float*)d_in[9];
    float* out = (float*)d_out;

    const int N = in_sizes[0] / FEAT;
    const int E = in_sizes[1] / 2;
    const int G = GRAPHS;
    const int NB = (N + (1 << BSH) - 1) >> BSH;
    const int* src = ei;
    const int* dst = ei + E;

    // workspace carve-up
    char* ws = (char*)d_ws;
    unsigned char* q8 = (unsigned char*)ws;                // N*128 int8 table
    float* srow = (float*)(q8 + (size_t)N * FEAT);         // N
    unsigned short* hact = (unsigned short*)(srow + N);    // N*128 bf16 activations
    int*   ssrc = (int*)(hact + (size_t)N * FEAT);         // E
    unsigned* stg = (unsigned*)(ssrc + E);                 // E
    int*   off  = (int*)(stg + E);                         // N
    int*   cnt  = off + N;                                 // N
    float* dinv = (float*)(cnt + N);                       // N
    int*   bhist = (int*)(dinv + N);                       // MAXNB
    int*   bbase = bhist + MAXNB;                          // MAXNB
    int*   bcur  = bbase + MAXNB;                          // MAXNB
    int*   gstart = bcur + MAXNB;                          // G+1
    unsigned short* wpre1 = (unsigned short*)(gstart + G + 2); // 16384
    unsigned short* wpre2 = wpre1 + 16384;                 // 16384

    const int nb = (N + 255) / 256;
    const int nch = (E + CH - 1) / CH;
    const int ngb = (N + 127) / 128;

    hipMemsetAsync(bhist, 0, (size_t)NB * sizeof(int), stream);

    // W pre-pack (independent)
    k_wpre<<<8, 256, 0, stream>>>(W1, wpre1);
    k_wpre<<<8, 256, 0, stream>>>(W2, wpre2);

    // CSR build
    kb_hist<<<256, 256, 0, stream>>>(dst, E, NB, bhist);
    kb_scan<<<1, 512, 0, stream>>>(bhist, NB, bbase, bcur);
    kb_group<<<nch, 256, 0, stream>>>(src, dst, E, NB, bcur, stg);
    kb_csr<<<NB, 256, 0, stream>>>(stg, bbase, bhist, N, ssrc, off, cnt, dinv);

    // graph boundaries
    k_gstart<<<nb, 256, 0, stream>>>(batch, N, G, gstart);

    // layer 1
    k_gemm_mfma<false><<<ngb, 256, 0, stream>>>(x, wpre1, dinv, q8, srow, N);
    k_agg8<<<(N * 8 + 255) / 256, 256, 0, stream>>>(q8, srow, off, cnt, ssrc, dinv, b1, (unsigned*)hact, N);
    // layer 2
    k_gemm_mfma<true><<<ngb, 256, 0, stream>>>(hact, wpre2, dinv, q8, srow, N);
    k_agg8<<<(N * 8 + 255) / 256, 256, 0, stream>>>(q8, srow, off, cnt, ssrc, dinv, b2, (unsigned*)hact, N);

    // fused pool + head
    k_pool_head<<<G, 256, 0, stream>>>((const unsigned*)hact, gstart, Wlin, blin, out, G);
}

// Round 10
// 306.898 us; speedup vs baseline: 2.7582x; 1.0372x over previous
//
#include <hip/hip_runtime.h>
#include <hip/hip_bf16.h>

// GCN: h1 = relu(gcnconv(x,W1,b1)); h2 = relu(gcnconv(h1,W2,b2));
// pooled = segment_mean(h2, batch); out = pooled@Wlin + blin
//
// R10: (1) agg8 8-deep explicit unroll -> 2x in-flight gather lines per wave
//      (2) k_setup fuses wpre x2 + bhist zeroing (14 -> 11 graph nodes)
// Keeps R9's int8 table + eighth-wave-per-node (2 lines/edge, 8 chains/wave).

#define FEAT 128
#define GRAPHS 256
#define CH 2048
#define BSH 8
#define MAXNB 512

typedef short bf16x8 __attribute__((ext_vector_type(8)));
typedef float f32x4 __attribute__((ext_vector_type(4)));

__device__ inline unsigned bf16rne(float f) {
    unsigned u = __float_as_uint(f);
    return (u + 0x7FFFu + ((u >> 16) & 1u)) >> 16;
}
__device__ inline float bfl(unsigned u) { return __uint_as_float(u << 16); }
__device__ inline float bfh(unsigned u) { return __uint_as_float(u & 0xFFFF0000u); }

#define SWZ(row, kbyte) ((kbyte) ^ (((row) & 7) << 4))

// ---------------- setup: W pre-pack (blocks 0-15) + bhist zero (block 16) ----------------
__global__ __launch_bounds__(256) void k_setup(const float* __restrict__ W1,
                                               const float* __restrict__ W2,
                                               unsigned short* __restrict__ wpre1,
                                               unsigned short* __restrict__ wpre2,
                                               int* __restrict__ bhist, int NB) {
    int b = blockIdx.x;
    if (b < 16) {
        const float* W = (b < 8) ? W1 : W2;
        unsigned short* Wp = (b < 8) ? wpre1 : wpre2;
        int tid = (b & 7) * 256 + threadIdx.x;   // 0..2047
        int frag = tid >> 6;
        int l = tid & 63;
        int cf = frag >> 2, ks = frag & 3;
        int col = cf * 16 + (l & 15);
        int k0 = ks * 32 + (l >> 4) * 8;
        unsigned short o[8];
#pragma unroll
        for (int j = 0; j < 8; ++j)
            o[j] = (unsigned short)bf16rne(W[(k0 + j) * 128 + col]);
        *(uint4*)(Wp + (size_t)tid * 8) = *(const uint4*)o;
    } else {
        for (int i = threadIdx.x; i < NB; i += 256) bhist[i] = 0;
    }
}

// ---------------- bucket histogram ----------------
__global__ __launch_bounds__(256) void kb_hist(const int* __restrict__ dst, int E, int NB,
                                               int* __restrict__ bhist) {
    __shared__ int h[MAXNB];
    for (int i = threadIdx.x; i < NB; i += 256) h[i] = 0;
    __syncthreads();
    int stride = gridDim.x * 256;
    for (int i = blockIdx.x * 256 + threadIdx.x; i < E; i += stride)
        atomicAdd(&h[dst[i] >> BSH], 1);
    __syncthreads();
    for (int i = threadIdx.x; i < NB; i += 256)
        if (h[i]) atomicAdd(&bhist[i], h[i]);
}

// ---------------- bucket base scan ----------------
__global__ void kb_scan(const int* __restrict__ bhist, int NB,
                        int* __restrict__ bbase, int* __restrict__ bcur) {
    __shared__ int s[512];
    int t = threadIdx.x;
    int v = (t < NB) ? bhist[t] : 0;
    s[t] = v;
    __syncthreads();
    for (int d = 1; d < 512; d <<= 1) {
        int a = (t >= d) ? s[t - d] : 0;
        __syncthreads();
        s[t] += a;
        __syncthreads();
    }
    if (t < NB) { int e = s[t] - v; bbase[t] = e; bcur[t] = e; }
}

// ---------------- group edges by bucket into staging (packed) ----------------
__global__ __launch_bounds__(256) void kb_group(const int* __restrict__ src,
                                                const int* __restrict__ dst, int E, int NB,
                                                int* __restrict__ bcur,
                                                unsigned* __restrict__ stg) {
    __shared__ int lhist[MAXNB], lcur[MAXNB], gdelta[MAXNB], sc[512];
    __shared__ unsigned lpak[CH];
    __shared__ int gp[CH];
    int t = threadIdx.x;
    int base = blockIdx.x * CH;
    int n = E - base; if (n > CH) n = CH;

    for (int i = t; i < NB; i += 256) lhist[i] = 0;
    __syncthreads();

    unsigned pk[8]; int bk[8]; int nl = 0;
#pragma unroll
    for (int j = 0; j < 8; ++j) {
        int k = j * 256 + t;
        if (k < n) {
            int d = dst[base + k];
            int sv = src[base + k];
            int b = d >> BSH;
            pk[nl] = ((unsigned)(d & ((1 << BSH) - 1)) << 17) | (unsigned)sv;
            bk[nl] = b; nl++;
            atomicAdd(&lhist[b], 1);
        }
    }
    __syncthreads();

    for (int i = t; i < 512; i += 256) sc[i] = (i < NB) ? lhist[i] : 0;
    __syncthreads();
    for (int d = 1; d < 512; d <<= 1) {
        int a0 = (t >= d) ? sc[t - d] : 0;
        int a1 = sc[t + 256 - d];
        __syncthreads();
        sc[t] += a0; sc[t + 256] += a1;
        __syncthreads();
    }
    for (int i = t; i < NB; i += 256) {
        int c = lhist[i];
        int lb = sc[i] - c;
        lcur[i] = lb;
        int g = c ? atomicAdd(&bcur[i], c) : 0;
        gdelta[i] = g - lb;
    }
    __syncthreads();

    for (int j = 0; j < nl; ++j) {
        int b = bk[j];
        int slot = atomicAdd(&lcur[b], 1);
        lpak[slot] = pk[j];
        gp[slot] = gdelta[b] + slot;
    }
    __syncthreads();
    for (int i = t; i < n; i += 256) stg[gp[i]] = lpak[i];
}

// ---------------- per-bucket counting sort -> ssrc, cnt, off, dinv ----------------
__global__ __launch_bounds__(256) void kb_csr(const unsigned* __restrict__ stg,
                                              const int* __restrict__ bbase,
                                              const int* __restrict__ bhist, int N,
                                              int* __restrict__ ssrc, int* __restrict__ off,
                                              int* __restrict__ cnt, float* __restrict__ dinv) {
    __shared__ int h[256], lcur[256], sc[256];
    int b = blockIdx.x;
    int t = threadIdx.x;
    int s0 = bbase[b], m = bhist[b];
    h[t] = 0;
    __syncthreads();
    for (int i = t; i < m; i += 256) atomicAdd(&h[stg[s0 + i] >> 17], 1);
    __syncthreads();
    int v = h[t];
    sc[t] = v;
    __syncthreads();
    for (int d = 1; d < 256; d <<= 1) {
        int a = (t >= d) ? sc[t - d] : 0;
        __syncthreads();
        sc[t] += a;
        __syncthreads();
    }
    int lb = sc[t] - v;
    lcur[t] = lb;
    int node = (b << BSH) + t;
    if (node < N) {
        off[node] = s0 + lb;
        cnt[node] = v;
        dinv[node] = rsqrtf(1.0f + (float)v);
    }
    __syncthreads();
    for (int i = t; i < m; i += 256) {
        unsigned p = stg[s0 + i];
        int d = p >> 17;
        int r = atomicAdd(&lcur[d], 1);
        ssrc[s0 + r] = (int)(p & 0x1FFFFu);
    }
}

// ---------------- graph boundaries from sorted batch ----------------
__global__ void k_gstart(const int* __restrict__ batch, int N, int G, int* __restrict__ gstart) {
    int i = blockIdx.x * blockDim.x + threadIdx.x;
    if (i >= N) return;
    int b = batch[i];
    int bp = (i == 0) ? -1 : batch[i - 1];
    for (int g = bp + 1; g <= b; ++g) gstart[g] = i;
    if (i == N - 1) {
        for (int g = b + 1; g <= G; ++g) gstart[g] = N;
    }
}

// ---------------- int8 helpers ----------------
__device__ inline unsigned umax16pair(unsigned d, unsigned cur) {
    unsigned a = d & 0x7FFF7FFFu;          // abs of two bf16 (no NaNs here)
    unsigned lo = a & 0xFFFFu, hi = a >> 16;
    unsigned m = lo > hi ? lo : hi;
    return m > cur ? m : cur;
}
__device__ inline unsigned q8b(float x, float si) {
    return (unsigned)(__float2int_rn(x * si) + 128) & 0xFFu;
}
__device__ inline unsigned pack2(unsigned d0, unsigned d1, float si) {
    float x0 = bfl(d0), x1 = bfh(d0), x2 = bfl(d1), x3 = bfh(d1);
    return q8b(x0, si) | (q8b(x1, si) << 8) | (q8b(x2, si) << 16) | (q8b(x3, si) << 24);
}

// ---------------- MFMA GEMM -> int8 row-scaled table ----------------
// Q8[row][c] = biased uint8 of (X@W)[row][c]*dinv[row];  srow[row] = rowmax/127
template <bool BF16IN>
__global__ __launch_bounds__(256, 4) void k_gemm_mfma(const void* __restrict__ Xv,
                                                      const unsigned short* __restrict__ Wpre,
                                                      const float* __restrict__ dinv,
                                                      unsigned char* __restrict__ Q8,
                                                      float* __restrict__ srow, int N) {
    __shared__ __align__(16) unsigned short sA[128 * 128];  // 32 KB
    __shared__ unsigned sMaxH[256];
    int t = threadIdx.x;
    int r0 = blockIdx.x * 128;
    int rows = N - r0; if (rows > 128) rows = 128;

    if constexpr (!BF16IN) {
        const float4* X4 = (const float4*)((const float*)Xv + (size_t)r0 * 128);
#pragma unroll
        for (int j = 0; j < 16; ++j) {
            int f = j * 256 + t;
            int row = f >> 5, q = f & 31;
            float4 v = make_float4(0.f, 0.f, 0.f, 0.f);
            if (row < rows) v = X4[f];
            unsigned lo = bf16rne(v.x) | (bf16rne(v.y) << 16);
            unsigned hi = bf16rne(v.z) | (bf16rne(v.w) << 16);
            int byte = row * 256 + SWZ(row, q * 8);
            *(uint2*)((char*)sA + byte) = make_uint2(lo, hi);
        }
    } else {
        const uint4* X4 = (const uint4*)((const unsigned short*)Xv + (size_t)r0 * 128);
#pragma unroll
        for (int j = 0; j < 8; ++j) {
            int f = j * 256 + t;
            int row = f >> 4, q = f & 15;
            uint4 v = make_uint4(0u, 0u, 0u, 0u);
            if (row < rows) v = X4[f];
            int byte = row * 256 + SWZ(row, q * 16);
            *(uint4*)((char*)sA + byte) = v;
        }
    }
    __syncthreads();

    int w = t >> 6, l = t & 63;
    int wr = (w >> 1) * 64, wc = (w & 1) * 64;
    int lr = l & 15, kc = l >> 4;

    f32x4 acc[4][4] = {};
    for (int ks = 0; ks < 4; ++ks) {
        bf16x8 a[4], b[4];
#pragma unroll
        for (int m = 0; m < 4; ++m) {
            int row = wr + m * 16 + lr;
            int byte = row * 256 + SWZ(row, ks * 64 + kc * 16);
            a[m] = *(const bf16x8*)((const char*)sA + byte);
        }
#pragma unroll
        for (int n = 0; n < 4; ++n) {
            int cf = (wc >> 4) + n;
            b[n] = *(const bf16x8*)(Wpre + ((size_t)((cf * 4 + ks) * 64 + l) * 8));
        }
#pragma unroll
        for (int m = 0; m < 4; ++m)
#pragma unroll
            for (int n = 0; n < 4; ++n)
                acc[m][n] = __builtin_amdgcn_mfma_f32_16x16x32_bf16(a[m], b[n], acc[m][n], 0, 0, 0);
    }
    __syncthreads();

    // phase 1: x dinv -> bf16 tile in LDS (linear)
#pragma unroll
    for (int m = 0; m < 4; ++m) {
        int rbase = wr + m * 16 + kc * 4;
#pragma unroll
        for (int r = 0; r < 4; ++r) {
            int row = rbase + r;
            float dv = (r0 + row < N) ? dinv[r0 + row] : 0.f;
#pragma unroll
            for (int n = 0; n < 4; ++n) {
                int col = wc + n * 16 + lr;
                sA[row * 128 + col] = (unsigned short)bf16rne(acc[m][n][r] * dv);
            }
        }
    }
    __syncthreads();

    // phase 2: rowmax + int8 quantize. thread t: row r=t>>1, half hh=t&1 (64 cols)
    {
        int r = t >> 1, hh = t & 1;
        const uint4* rowp = (const uint4*)(sA + r * 128 + hh * 64);
        uint4 wreg[8];
#pragma unroll
        for (int j = 0; j < 8; ++j) wreg[j] = rowp[j];
        unsigned mb = 0;
#pragma unroll
        for (int j = 0; j < 8; ++j) {
            mb = umax16pair(wreg[j].x, mb);
            mb = umax16pair(wreg[j].y, mb);
            mb = umax16pair(wreg[j].z, mb);
            mb = umax16pair(wreg[j].w, mb);
        }
        sMaxH[r * 2 + hh] = mb;
        __syncthreads();
        unsigned m0 = sMaxH[r * 2], m1 = sMaxH[r * 2 + 1];
        unsigned m16 = m0 > m1 ? m0 : m1;
        float mv = __uint_as_float(m16 << 16);
        float si = (mv > 0.f) ? 127.0f / mv : 0.0f;
        if (hh == 0 && r0 + r < N) srow[r0 + r] = mv * (1.0f / 127.0f);
        if (r0 + r < N) {
            unsigned q[16];
#pragma unroll
            for (int j = 0; j < 8; ++j) {
                q[2 * j]     = pack2(wreg[j].x, wreg[j].y, si);
                q[2 * j + 1] = pack2(wreg[j].z, wreg[j].w, si);
            }
            uint4* qo = (uint4*)(Q8 + (size_t)(r0 + r) * 128 + hh * 64);
            qo[0] = make_uint4(q[0], q[1], q[2], q[3]);
            qo[1] = make_uint4(q[4], q[5], q[6], q[7]);
            qo[2] = make_uint4(q[8], q[9], q[10], q[11]);
            qo[3] = make_uint4(q[12], q[13], q[14], q[15]);
        }
    }
}

// ---------------- aggregation: eighth-wave per node, int8 table, 8-deep ----------------
#define ACCU(u, s, A, B, C, D) {                      \
    A = fmaf(s, (float)((u) & 0xFFu), A);             \
    B = fmaf(s, (float)(((u) >> 8) & 0xFFu), B);      \
    C = fmaf(s, (float)(((u) >> 16) & 0xFFu), C);     \
    D = fmaf(s, (float)((u) >> 24), D); }
#define ACCROW8(R, S) { float _s = (S); ssum += _s;   \
    ACCU(R.x, _s, a0, a1, a2, a3)                     \
    ACCU(R.y, _s, a4, a5, a6, a7)                     \
    ACCU(R.z, _s, a8, a9, a10, a11)                   \
    ACCU(R.w, _s, a12, a13, a14, a15) }

__global__ __launch_bounds__(256) void k_agg8(const unsigned char* __restrict__ Q8,
                                              const float* __restrict__ srow,
                                              const int* __restrict__ off,
                                              const int* __restrict__ cnt,
                                              const int* __restrict__ ssrc,
                                              const float* __restrict__ dinv,
                                              const float* __restrict__ b,
                                              unsigned* __restrict__ OUTB, int N) {
    int v = (blockIdx.x * blockDim.x + threadIdx.x) >> 3;
    if (v >= N) return;
    int j = threadIdx.x & 7;            // 16 cols: j*16 .. j*16+15

    float a0 = 0.f, a1 = 0.f, a2 = 0.f, a3 = 0.f, a4 = 0.f, a5 = 0.f, a6 = 0.f, a7 = 0.f;
    float a8 = 0.f, a9 = 0.f, a10 = 0.f, a11 = 0.f, a12 = 0.f, a13 = 0.f, a14 = 0.f, a15 = 0.f;
    float ssum = 0.f;

    {   // self term
        uint4 r = *(const uint4*)(Q8 + (size_t)v * 128 + j * 16);
        float s = srow[v];
        ACCROW8(r, s)
    }
    int i = off[v], e = i + cnt[v];
    // 8-deep: issue all 17 loads (2 idx + 8 rows + 8 scales... idx first) before any use
    for (; i + 8 <= e; i += 8) {
        int4 ua = *(const int4*)(ssrc + i);
        int4 ub = *(const int4*)(ssrc + i + 4);
        uint4 r0 = *(const uint4*)(Q8 + (size_t)ua.x * 128 + j * 16);
        uint4 r1 = *(const uint4*)(Q8 + (size_t)ua.y * 128 + j * 16);
        uint4 r2 = *(const uint4*)(Q8 + (size_t)ua.z * 128 + j * 16);
        uint4 r3 = *(const uint4*)(Q8 + (size_t)ua.w * 128 + j * 16);
        uint4 r4 = *(const uint4*)(Q8 + (size_t)ub.x * 128 + j * 16);
        uint4 r5 = *(const uint4*)(Q8 + (size_t)ub.y * 128 + j * 16);
        uint4 r6 = *(const uint4*)(Q8 + (size_t)ub.z * 128 + j * 16);
        uint4 r7 = *(const uint4*)(Q8 + (size_t)ub.w * 128 + j * 16);
        float s0 = srow[ua.x], s1 = srow[ua.y], s2 = srow[ua.z], s3 = srow[ua.w];
        float s4 = srow[ub.x], s5 = srow[ub.y], s6 = srow[ub.z], s7 = srow[ub.w];
        ACCROW8(r0, s0) ACCROW8(r1, s1) ACCROW8(r2, s2) ACCROW8(r3, s3)
        ACCROW8(r4, s4) ACCROW8(r5, s5) ACCROW8(r6, s6) ACCROW8(r7, s7)
    }
    if (i + 4 <= e) {
        int4 ua = *(const int4*)(ssrc + i);
        uint4 r0 = *(const uint4*)(Q8 + (size_t)ua.x * 128 + j * 16);
        uint4 r1 = *(const uint4*)(Q8 + (size_t)ua.y * 128 + j * 16);
        uint4 r2 = *(const uint4*)(Q8 + (size_t)ua.z * 128 + j * 16);
        uint4 r3 = *(const uint4*)(Q8 + (size_t)ua.w * 128 + j * 16);
        float s0 = srow[ua.x], s1 = srow[ua.y], s2 = srow[ua.z], s3 = srow[ua.w];
        ACCROW8(r0, s0) ACCROW8(r1, s1) ACCROW8(r2, s2) ACCROW8(r3, s3)
        i += 4;
    }
    for (; i < e; ++i) {
        int u = ssrc[i];
        uint4 r = *(const uint4*)(Q8 + (size_t)u * 128 + j * 16);
        float s = srow[u];
        ACCROW8(r, s)
    }

    float dv = dinv[v];
    float corr = 128.f * ssum;
    const float4* B4 = (const float4*)(b + j * 16);
    float4 bb0 = B4[0], bb1 = B4[1], bb2 = B4[2], bb3 = B4[3];
    float o0  = fmaxf((a0  - corr) * dv + bb0.x, 0.f);
    float o1  = fmaxf((a1  - corr) * dv + bb0.y, 0.f);
    float o2  = fmaxf((a2  - corr) * dv + bb0.z, 0.f);
    float o3  = fmaxf((a3  - corr) * dv + bb0.w, 0.f);
    float o4  = fmaxf((a4  - corr) * dv + bb1.x, 0.f);
    float o5  = fmaxf((a5  - corr) * dv + bb1.y, 0.f);
    float o6  = fmaxf((a6  - corr) * dv + bb1.z, 0.f);
    float o7  = fmaxf((a7  - corr) * dv + bb1.w, 0.f);
    float o8  = fmaxf((a8  - corr) * dv + bb2.x, 0.f);
    float o9  = fmaxf((a9  - corr) * dv + bb2.y, 0.f);
    float o10 = fmaxf((a10 - corr) * dv + bb2.z, 0.f);
    float o11 = fmaxf((a11 - corr) * dv + bb2.w, 0.f);
    float o12 = fmaxf((a12 - corr) * dv + bb3.x, 0.f);
    float o13 = fmaxf((a13 - corr) * dv + bb3.y, 0.f);
    float o14 = fmaxf((a14 - corr) * dv + bb3.z, 0.f);
    float o15 = fmaxf((a15 - corr) * dv + bb3.w, 0.f);

    uint4 w0, w1;
    w0.x = bf16rne(o0)  | (bf16rne(o1)  << 16);
    w0.y = bf16rne(o2)  | (bf16rne(o3)  << 16);
    w0.z = bf16rne(o4)  | (bf16rne(o5)  << 16);
    w0.w = bf16rne(o6)  | (bf16rne(o7)  << 16);
    w1.x = bf16rne(o8)  | (bf16rne(o9)  << 16);
    w1.y = bf16rne(o10) | (bf16rne(o11) << 16);
    w1.z = bf16rne(o12) | (bf16rne(o13) << 16);
    w1.w = bf16rne(o14) | (bf16rne(o15) << 16);
    uint4* orow = (uint4*)OUTB + (size_t)v * 16 + j * 2;
    orow[0] = w0;
    orow[1] = w1;
}

// ---------------- fused segmented-mean pool + linear head (bf16 input) ----------------
__global__ __launch_bounds__(256) void k_pool_head(const unsigned* __restrict__ H2,
                                                   const int* __restrict__ gstart,
                                                   const float* __restrict__ Wlin,
                                                   const float* __restrict__ blin,
                                                   float* __restrict__ out, int G) {
    __shared__ float2 stmp[256];
    __shared__ float sp[128];
    int g = blockIdx.x;
    int t = threadIdx.x;
    int p = t & 63, quarter = t >> 6;
    int s = gstart[g], e = gstart[g + 1];
    float2 acc = make_float2(0.f, 0.f);
    for (int i = s + quarter; i < e; i += 4) {
        unsigned u = H2[(size_t)i * 64 + p];
        acc.x += bfl(u);
        acc.y += bfh(u);
    }
    stmp[t] = acc;
    __syncthreads();
    if (t < 64) {
        float2 a = stmp[t];
        a.x += stmp[t + 64].x + stmp[t + 128].x + stmp[t + 192].x;
        a.y += stmp[t + 64].y + stmp[t + 128].y + stmp[t + 192].y;
        float inv = 1.0f / fmaxf((float)(e - s), 1.0f);
        sp[2 * t] = a.x * inv;
        sp[2 * t + 1] = a.y * inv;
    }
    __syncthreads();
    if (t < 2) {
        float a = 0.0f;
        for (int j = 0; j < 128; ++j) a += sp[j] * Wlin[j * 2 + t];
        out[g * 2 + t] = a + blin[t];
    }
}

extern "C" void kernel_launch(void* const* d_in, const int* in_sizes, int n_in,
                              void* d_out, int out_size, void* d_ws, size_t ws_size,
                              hipStream_t stream) {
    const float* x     = (const float*)d_in[0];
    const int*   ei    = (const int*)d_in[1];   // [2,E]
    const int*   batch = (const int*)d_in[2];   // [N]
    const float* W1    = (const float*)d_in[4];
    const float* b1    = (const float*)d_in[5];
    const float* W2    = (const float*)d_in[6];
    const float* b2    = (const float*)d_in[7];
    const float* Wlin  = (const float*)d_in[8];
    const float* blin  = (const float*)d_in[9];
    float* out = (float*)d_out;

    const int N = in_sizes[0] / FEAT;
    const int E = in_sizes[1] / 2;
    const int G = GRAPHS;
    const int NB = (N + (1 << BSH) - 1) >> BSH;
    const int* src = ei;
    const int* dst = ei + E;

    // workspace carve-up
    char* ws = (char*)d_ws;
    unsigned char* q8 = (unsigned char*)ws;                // N*128 int8 table
    float* srow = (float*)(q8 + (size_t)N * FEAT);         // N
    unsigned short* hact = (unsigned short*)(srow + N);    // N*128 bf16 activations
    int*   ssrc = (int*)(hact + (size_t)N * FEAT);         // E
    unsigned* stg = (unsigned*)(ssrc + E);                 // E
    int*   off  = (int*)(stg + E);                         // N
    int*   cnt  = off + N;                                 // N
    float* dinv = (float*)(cnt + N);                       // N
    int*   bhist = (int*)(dinv + N);                       // MAXNB
    int*   bbase = bhist + MAXNB;                          // MAXNB
    int*   bcur  = bbase + MAXNB;                          // MAXNB
    int*   gstart = bcur + MAXNB;                          // G+1
    unsigned short* wpre1 = (unsigned short*)(gstart + G + 2); // 16384
    unsigned short* wpre2 = wpre1 + 16384;                 // 16384

    const int nb = (N + 255) / 256;
    const int nch = (E + CH - 1) / CH;
    const int ngb = (N + 127) / 128;

    // setup: wpre x2 + bhist zero (one kernel)
    k_setup<<<17, 256, 0, stream>>>(W1, W2, wpre1, wpre2, bhist, NB);

    // CSR build
    kb_hist<<<256, 256, 0, stream>>>(dst, E, NB, bhist);
    kb_scan<<<1, 512, 0, stream>>>(bhist, NB, bbase, bcur);
    kb_group<<<nch, 256, 0, stream>>>(src, dst, E, NB, bcur, stg);
    kb_csr<<<NB, 256, 0, stream>>>(stg, bbase, bhist, N, ssrc, off, cnt, dinv);

    // graph boundaries
    k_gstart<<<nb, 256, 0, stream>>>(batch, N, G, gstart);

    // layer 1
    k_gemm_mfma<false><<<ngb, 256, 0, stream>>>(x, wpre1, dinv, q8, srow, N);
    k_agg8<<<(N * 8 + 255) / 256, 256, 0, stream>>>(q8, srow, off, cnt, ssrc, dinv, b1, (unsigned*)hact, N);
    // layer 2
    k_gemm_mfma<true><<<ngb, 256, 0, stream>>>(hact, wpre2, dinv, q8, srow, N);
    k_agg8<<<(N * 8 + 255) / 256, 256, 0, stream>>>(q8, srow, off, cnt, ssrc, dinv, b2, (unsigned*)hact, N);

    // fused pool + head
    k_pool_head<<<G, 256, 0, stream>>>((const unsigned*)hact, gstart, Wlin, blin, out, G);
}